// Round 4
// baseline (344.155 us; speedup 1.0000x reference)
//
#include <hip/hip_runtime.h>

#define HW   3136   // 56*56
#define HW4  784    // uint4 vectors per row
#define KSEL 313    // int(0.1 * 3136)
#define NT   256

typedef unsigned uint4n __attribute__((ext_vector_type(4)));  // native vec for NT stores

__global__ __launch_bounds__(NT, 8)
void topk_mask_kernel(const uint4* __restrict__ x, uint4* __restrict__ out) {
  __shared__ unsigned hist[256];
  __shared__ unsigned red[4];
  __shared__ unsigned sel[2];     // [0]=crossing bin (or ~0), [1]=rank needed in bin
  __shared__ unsigned gval[64];   // full signed values of threshold-bin members
  __shared__ unsigned gidxs[64];  // their global indices
  __shared__ unsigned gcnt;

  const int tid  = threadIdx.x;
  const int lane = tid & 63;
  const int wv   = tid >> 6;
  const size_t row = blockIdx.x;
  const uint4* __restrict__ src = x + row * (size_t)HW4;
  uint4* __restrict__ dst = out + row * (size_t)HW4;

  // ---- row resident in registers ----
  uint4 d0 = src[tid];
  uint4 d1 = src[tid + 256];
  uint4 d2 = src[tid + 512];
  uint4 d3 = (tid < 16) ? src[768 + tid] : make_uint4(0u, 0u, 0u, 0u);  // pad: bin 0

  hist[tid] = 0u;
  if (tid == 0) { gcnt = 0u; sel[0] = 0xFFFFFFFFu; }
  __syncthreads();                                    // B1

  // ---- pass 1: histogram over |x| in [1.3, 2.0), bins packed 4x8b per reg ----
  const float LB = 1.3f;
  const float SC = 254.0f / 0.7f;
  auto binof = [&](unsigned w) -> unsigned {
    unsigned key = w & 0x7FFFFFFFu;
    float a = __uint_as_float(key);
    if (a < LB) return 0u;                            // below bracket: surely dropped
    int b = 1 + (int)((fminf(a, 2.1f) - LB) * SC);
    return (b > 255) ? 255u : (unsigned)b;
  };
  auto packhist = [&](uint4 v) -> unsigned {
    unsigned b0 = binof(v.x), b1 = binof(v.y), b2 = binof(v.z), b3 = binof(v.w);
    if (b0) atomicAdd(&hist[b0], 1u);
    if (b1) atomicAdd(&hist[b1], 1u);
    if (b2) atomicAdd(&hist[b2], 1u);
    if (b3) atomicAdd(&hist[b3], 1u);
    return b0 | (b1 << 8) | (b2 << 16) | (b3 << 24);
  };
  unsigned bp0 = packhist(d0);
  unsigned bp1 = packhist(d1);
  unsigned bp2 = packhist(d2);
  unsigned bp3 = packhist(d3);                        // zeros for tid>=16: no atomics
  __syncthreads();                                    // B2

  // ---- suffix scan S[b] = count(bin >= b); find crossing bin for KSEL ----
  unsigned c  = (tid == 0) ? 0u : hist[tid];
  unsigned sv = c;
#pragma unroll
  for (int off = 1; off < 64; off <<= 1) {
    unsigned u = __shfl_down(sv, off);
    if (lane + off < 64) sv += u;
  }
  if (lane == 0) red[wv] = sv;
  __syncthreads();                                    // B3
  unsigned S = sv;
  for (int w = wv + 1; w < 4; ++w) S += red[w];
  unsigned S1 = S - c;
  if (tid >= 1 && S >= KSEL && S1 < KSEL) {           // unique crossing bin
    sel[0] = (unsigned)tid;
    sel[1] = KSEL - S1;                               // members of bin to keep (>=1)
  }
  __syncthreads();                                    // B4

  const unsigned bsel = sel[0];
  bool fast = (bsel != 0xFFFFFFFFu);
  if (fast) {
    const unsigned krb = sel[1];
    // ---- fused output + gather: bins>bsel keep, <bsel zero, ==bsel zero+push ----
    auto emit = [&](uint4 v, unsigned bp, unsigned e0, bool doStore, uint4* outp) {
      unsigned b0 = bp & 255u, b1 = (bp >> 8) & 255u, b2 = (bp >> 16) & 255u, b3 = bp >> 24;
      uint4n o;
      o.x = (b0 > bsel) ? v.x : 0u;
      o.y = (b1 > bsel) ? v.y : 0u;
      o.z = (b2 > bsel) ? v.z : 0u;
      o.w = (b3 > bsel) ? v.w : 0u;
      if (b0 == bsel) { unsigned p = atomicAdd(&gcnt, 1u); if (p < 64u) { gval[p] = v.x; gidxs[p] = e0 + 0u; } }
      if (b1 == bsel) { unsigned p = atomicAdd(&gcnt, 1u); if (p < 64u) { gval[p] = v.y; gidxs[p] = e0 + 1u; } }
      if (b2 == bsel) { unsigned p = atomicAdd(&gcnt, 1u); if (p < 64u) { gval[p] = v.z; gidxs[p] = e0 + 2u; } }
      if (b3 == bsel) { unsigned p = atomicAdd(&gcnt, 1u); if (p < 64u) { gval[p] = v.w; gidxs[p] = e0 + 3u; } }
      if (doStore)
        __builtin_nontemporal_store(o, reinterpret_cast<uint4n*>(outp));  // write-once stream
    };
    emit(d0, bp0, 4u * (unsigned)tid,         true,      &dst[tid]);
    emit(d1, bp1, 4u * (unsigned)(tid + 256), true,      &dst[tid + 256]);
    emit(d2, bp2, 4u * (unsigned)(tid + 512), true,      &dst[tid + 512]);
    emit(d3, bp3, 4u * (unsigned)(768 + tid), tid < 16,  &dst[768 + tid]);
    __syncthreads();                                  // B5: glist ready, stores drained
    const unsigned cnt = gcnt;
    if (cnt <= 64u) {
      // ---- wave 0: rank bin members (key desc, idx asc) and patch winners back ----
      if (tid < 64) {
        unsigned kv = (tid < (int)cnt) ? (gval[tid] & 0x7FFFFFFFu) : 0u;
        unsigned gi = (tid < (int)cnt) ? gidxs[tid] : 0xFFFFFFFFu;
        unsigned rank = 0;
        for (int i = 0; i < (int)cnt; ++i) {
          unsigned u = __shfl(kv, i);
          unsigned g = __shfl(gi, i);
          rank += (u > kv || (u == kv && g < gi)) ? 1u : 0u;
        }
        if (tid < (int)cnt && rank < krb)
          reinterpret_cast<unsigned*>(dst)[gi] = gval[tid];   // restore kept member
      }
      return;                                         // block-uniform exit
    }
    fast = false;                                     // glist overflow: rare, redo exactly
  }

  // ---- correct-for-anything fallback: bisection, then full rewrite ----
  auto count_ge = [&](unsigned v) -> unsigned {
    unsigned cc = 0;
    uint4 dd[4] = {d0, d1, d2, d3};
#pragma unroll
    for (int q = 0; q < 4; ++q) {
      cc += ((dd[q].x & 0x7FFFFFFFu) >= v);
      cc += ((dd[q].y & 0x7FFFFFFFu) >= v);
      cc += ((dd[q].z & 0x7FFFFFFFu) >= v);
      cc += ((dd[q].w & 0x7FFFFFFFu) >= v);
    }
#pragma unroll
    for (int off = 32; off > 0; off >>= 1) cc += __shfl_xor(cc, off);
    __syncthreads();
    if (lane == 0) red[wv] = cc;
    __syncthreads();
    return red[0] + red[1] + red[2] + red[3];
  };
  auto count_eq_le = [&](unsigned t, unsigned m) -> unsigned {
    unsigned cc = 0;
    uint4 dd[4] = {d0, d1, d2, d3};
#pragma unroll
    for (int q = 0; q < 4; ++q) {
      const unsigned vec = (q < 3) ? (unsigned)(tid + (q << 8)) : (unsigned)(768 + tid);
      const unsigned e0 = vec * 4u;
      cc += (((dd[q].x & 0x7FFFFFFFu) == t) && (e0 + 0u <= m));
      cc += (((dd[q].y & 0x7FFFFFFFu) == t) && (e0 + 1u <= m));
      cc += (((dd[q].z & 0x7FFFFFFFu) == t) && (e0 + 2u <= m));
      cc += (((dd[q].w & 0x7FFFFFFFu) == t) && (e0 + 3u <= m));
    }
#pragma unroll
    for (int off = 32; off > 0; off >>= 1) cc += __shfl_xor(cc, off);
    __syncthreads();
    if (lane == 0) red[wv] = cc;
    __syncthreads();
    return red[0] + red[1] + red[2] + red[3];
  };

  unsigned lo = 0u, hi = 0x80000000u;                 // f(lo) true, f(hi) false
  while (hi - lo > 1u) {
    unsigned mid = lo + ((hi - lo) >> 1);
    if (count_ge(mid) >= KSEL) lo = mid; else hi = mid;
  }
  unsigned t = lo, idx_cut;
  if (t == 0u) {
    idx_cut = 0xFFFFFFFFu;                            // fewer than K nonzeros: keep all
  } else {
    unsigned cgt = (t >= 0x7FFFFFFFu) ? 0u : count_ge(t + 1u);
    unsigned need_eq = KSEL - cgt;                    // >= 1
    unsigned ilo = 0u, ihi = HW - 1u;
    while (ilo < ihi) {
      unsigned im = (ilo + ihi) >> 1;
      if (count_eq_le(t, im) >= need_eq) ihi = im; else ilo = im + 1u;
    }
    idx_cut = ilo;
  }

  // full rewrite (same-thread program order supersedes speculative stores)
  {
    uint4 dd[4] = {d0, d1, d2, d3};
#pragma unroll
    for (int q = 0; q < 4; ++q) {
      const unsigned vec = (q < 3) ? (unsigned)(tid + (q << 8)) : (unsigned)(768 + tid);
      const unsigned e0 = vec * 4u;
      uint4 v = dd[q];
      unsigned k0 = v.x & 0x7FFFFFFFu, k1 = v.y & 0x7FFFFFFFu;
      unsigned k2 = v.z & 0x7FFFFFFFu, k3 = v.w & 0x7FFFFFFFu;
      v.x = (k0 > t || (k0 == t && e0 + 0u <= idx_cut)) ? v.x : 0u;
      v.y = (k1 > t || (k1 == t && e0 + 1u <= idx_cut)) ? v.y : 0u;
      v.z = (k2 > t || (k2 == t && e0 + 2u <= idx_cut)) ? v.z : 0u;
      v.w = (k3 > t || (k3 == t && e0 + 3u <= idx_cut)) ? v.w : 0u;
      if (q < 3)         dst[tid + (q << 8)] = v;
      else if (tid < 16) dst[768 + tid]      = v;
    }
  }
}

extern "C" void kernel_launch(void* const* d_in, const int* in_sizes, int n_in,
                              void* d_out, int out_size, void* d_ws, size_t ws_size,
                              hipStream_t stream) {
  const uint4* x = (const uint4*)d_in[0];
  uint4* out = (uint4*)d_out;
  const int rows = in_sizes[0] / HW;   // 16384
  hipLaunchKernelGGL(topk_mask_kernel, dim3(rows), dim3(NT), 0, stream, x, out);
}